// Round 3
// baseline (552.919 us; speedup 1.0000x reference)
//
#include <hip/hip_runtime.h>

#define NTAGS 48
#define NB    512
#define SLEN  2048

// ---------- cross-lane helpers (wave64, DPP) ----------

__device__ __forceinline__ float rl_f(float v, int l) {
  return __builtin_bit_cast(float, __builtin_amdgcn_readlane(__builtin_bit_cast(int, v), l));
}

template <int CTRL, bool BC>
__device__ __forceinline__ float dpp_mv(float oldv, float v) {
  return __builtin_bit_cast(float, __builtin_amdgcn_update_dpp(
      __builtin_bit_cast(int, oldv), __builtin_bit_cast(int, v), CTRL, 0xF, 0xF, BC));
}

__device__ __forceinline__ float wred_max(float v) {
  v = fmaxf(v, dpp_mv<0x128, false>(v, v));
  v = fmaxf(v, dpp_mv<0x124, false>(v, v));
  v = fmaxf(v, dpp_mv<0x122, false>(v, v));
  v = fmaxf(v, dpp_mv<0x121, false>(v, v));
  v = fmaxf(v, dpp_mv<0x142, false>(v, v));
  v = fmaxf(v, dpp_mv<0x143, false>(v, v));
  return rl_f(v, 63);
}

__device__ __forceinline__ float wred_sum(float v) {
  v += dpp_mv<0x128, true>(0.0f, v);
  v += dpp_mv<0x124, true>(0.0f, v);
  v += dpp_mv<0x122, true>(0.0f, v);
  v += dpp_mv<0x121, true>(0.0f, v);
  v += dpp_mv<0x142, true>(0.0f, v);
  v += dpp_mv<0x143, true>(0.0f, v);
  return rl_f(v, 63);
}

// row_ror:1 — full-rate VALU rotate within each 16-lane row:
// dst[lane] = src[row_base + ((lane&15)+1)&15]
__device__ __forceinline__ float ror1(float v) {
  return dpp_mv<0x121, false>(v, v);
}

// 48-wide matvec via DPP row rotations (no SGPR writes on the chain).
// Layout: lane = 16*r + c; p[lane] = alpha_tag(lane) for lane<48, pad rows hold
// junk that is NEVER consumed by real lanes:
//   phase0: S=A(own row r), phase1: S=(r==2)?C:B, phase2: S=(r==0)?C:D
//   where B=p[lane^16], C=p[lane^32], D=p[lane^48] via ds_bpermute.
//   row0 sees rows {0,1,2}, row1 {1,0,2}, row2 {2,0,1}  (row 3 never sourced).
// After k rotations lane c holds the source row's position (c+k)&15, i.e. tag
// 16*drow(phase,r) + ((c+k)&15); Evp[] is pre-permuted per lane to match.
__device__ __forceinline__ float rotdot48(float p, const float* Evp,
                                          int a16, int a32, int a48,
                                          bool isr2, bool isr0) {
  const int pi = __builtin_bit_cast(int, p);
  const float Bf = __builtin_bit_cast(float, __builtin_amdgcn_ds_bpermute(a16, pi));
  const float Cf = __builtin_bit_cast(float, __builtin_amdgcn_ds_bpermute(a32, pi));
  const float Df = __builtin_bit_cast(float, __builtin_amdgcn_ds_bpermute(a48, pi));
  float a0 = 0.f, a1 = 0.f, a2 = 0.f, a3 = 0.f, a4 = 0.f, a5 = 0.f;
  float s = p;  // phase 0 needs only p -> runs while bpermutes are in flight
#pragma unroll
  for (int k = 0; k < 16; ++k) {
    if (k & 1) a1 = fmaf(s, Evp[k], a1); else a0 = fmaf(s, Evp[k], a0);
    if (k < 15) s = ror1(s);
  }
  float t = isr2 ? Cf : Bf;
#pragma unroll
  for (int k = 0; k < 16; ++k) {
    if (k & 1) a3 = fmaf(t, Evp[16 + k], a3); else a2 = fmaf(t, Evp[16 + k], a2);
    if (k < 15) t = ror1(t);
  }
  float u = isr0 ? Cf : Df;
#pragma unroll
  for (int k = 0; k < 16; ++k) {
    if (k & 1) a5 = fmaf(u, Evp[32 + k], a5); else a4 = fmaf(u, Evp[32 + k], a4);
    if (k < 15) u = ror1(u);
  }
  return ((a0 + a1) + (a2 + a3)) + (a4 + a5);
}

// exact pow2 renorm: p *= 2^-e, cl += e*ln2
__device__ __forceinline__ void renorm(float& p, float& cl) {
  float mx = wred_max(p);
  int e = ((__builtin_bit_cast(int, mx) >> 23) & 255) - 127;
  float r = __builtin_bit_cast(float, (127 - e) << 23);
  p *= r;
  cl += (float)e * 0.6931471805599453f;
}

// ---------- fused kernel ----------
// blocks [0,1024): scan. even = forward half (alpha_1024), odd = backward half (beta_1024).
// blocks [1024,1536): gold-path score + mask count, one wave per batch.

extern "C" __global__ __launch_bounds__(64, 1)
void crf_main(const float* __restrict__ emis,
              const float* __restrict__ trans,
              const float* __restrict__ startt,
              const float* __restrict__ endt,
              const int*   __restrict__ tags,
              const float* __restrict__ mask,
              float* __restrict__ wa, float* __restrict__ wb,
              float* __restrict__ wsc, int* __restrict__ wcnt) {
  __shared__ float st[NTAGS * NTAGS];
  const int lane = threadIdx.x;
  const int bid  = blockIdx.x;

  if (bid >= 2 * NB) {
    // ----- score path -----
    const int b = bid - 2 * NB;
    for (int k = lane; k < NTAGS * NTAGS; k += 64) st[k] = trans[k];
    __syncthreads();
    const int* tb = tags + (size_t)b * SLEN;
    float ssum = 0.0f, csum = 0.0f;
    for (int it = 0; it < SLEN / 64; ++it) {
      const int t   = it * 64 + lane;
      int   cur = tb[t];
      float mv  = mask[(size_t)b * SLEN + t];
      float ev  = emis[((size_t)b * SLEN + t) * NTAGS + cur];
      float s;
      if (t == 0) {
        s = startt[cur] + ev;  // unmasked per reference
      } else {
        int prev = tb[t - 1];
        s = (mv != 0.0f) ? (st[prev * NTAGS + cur] + ev) : 0.0f;
      }
      ssum += s;
      csum += (mv != 0.0f) ? 1.0f : 0.0f;
    }
    ssum = wred_sum(ssum);
    csum = wred_sum(csum);
    if (lane == 0) { wsc[b] = ssum; wcnt[b] = (int)(csum + 0.5f); }
    return;
  }

  // ----- scan path -----
  const int  b   = bid >> 1;
  const bool fwd = (bid & 1) == 0;
  const int  r   = lane >> 4, c = lane & 15;
  const bool isr2 = (r == 2), isr0 = (r == 0);
  const int  a16 = (lane ^ 16) << 2;
  const int  a32 = (lane ^ 32) << 2;
  const int  a48 = (lane ^ 48) << 2;
  const int  jc  = lane < NTAGS ? lane : (NTAGS - 1);  // pad lanes mirror lane 47

  const float* eb = emis + (size_t)b * SLEN * NTAGS;
  const float* mb = mask + (size_t)b * SLEN;

  // per-lane pre-permuted exp(trans) table matching the rotation schedule
  float Evp[48];
  {
    const int d0 = r;
    const int d1 = isr2 ? 0 : (r ^ 1);
    const int d2 = isr0 ? 2 : (r ^ 3);
    const int drs[3] = {d0, d1, d2};
#pragma unroll
    for (int ph = 0; ph < 3; ++ph) {
#pragma unroll
      for (int k = 0; k < 16; ++k) {
        int i = 16 * drs[ph] + ((c + k) & 15);
        if (i > 47) i = 47;  // pad rows only; their products multiply pad data
        Evp[ph * 16 + k] = __expf(fwd ? trans[i * NTAGS + jc]
                                      : trans[jc * NTAGS + i]);
      }
    }
  }

  float ebuf[8];  // 8-deep emission prefetch ring, slot = t & 7
  float p, cl, een;

  if (fwd) {
    float mnext = mb[1 + (lane & 7)];  // masks for group 0 (bits 0..7 of ballot)
    float a0 = startt[jc] + eb[jc];
    if (lane >= NTAGS) a0 = -1e30f;
    float m0 = wred_max(a0);
    p  = __expf(a0 - m0);   // pad lanes: exp(-1e30-m0) = 0 -> stay harmless
    cl = m0;
#pragma unroll
    for (int k = 1; k <= 8; ++k) ebuf[k & 7] = eb[(size_t)k * NTAGS + jc];
    een = __expf(ebuf[1]);  // exp(emit_1)

    for (int g = 0; g < 128; ++g) {
      const int t0 = 1 + 8 * g;
      const uint32_t m8 = (uint32_t)__ballot(mnext != 0.0f) & 0xffu;
      mnext = mb[(size_t)(t0 + 8) + (lane & 7)];   // prefetch next group's masks
      if (m8 == 0xffu) {
        // fast path: all masked-in, no select on the chain
#pragma unroll
        for (int u = 0; u < 8; ++u) {
          const int t = t0 + u;
          float ee = een;                       // exp(emit_t), off-chain
          een = __expf(ebuf[(t + 1) & 7]);
          float acc = rotdot48(p, Evp, a16, a32, a48, isr2, isr0);
          p = acc * ee;
          ebuf[t & 7] = eb[(size_t)(t + 8) * NTAGS + jc];  // prefetch t+8
          if (u == 7) renorm(p, cl);
        }
      } else {
#pragma unroll
        for (int u = 0; u < 8; ++u) {
          const int t = t0 + u;
          float ee = een;
          een = __expf(ebuf[(t + 1) & 7]);
          float acc = rotdot48(p, Evp, a16, a32, a48, isr2, isr0);
          float pn  = acc * ee;
          p = ((m8 >> u) & 1u) ? pn : p;
          ebuf[t & 7] = eb[(size_t)(t + 8) * NTAGS + jc];
          if (u == 7) renorm(p, cl);
        }
      }
    }
    if (lane < NTAGS) wa[b * NTAGS + lane] = __logf(p) + cl;
  } else {
    float mnext = mb[2040 - (lane & 7)];  // masks for group 0 of main loop
    float b0 = endt[jc];
    if (lane >= NTAGS) b0 = -1e30f;
    float m0 = wred_max(b0);
    p  = __expf(b0 - m0);
    cl = m0;
#pragma unroll
    for (int k = 0; k < 8; ++k) ebuf[(2047 - k) & 7] = eb[(size_t)(2047 - k) * NTAGS + jc];
    float q = p * __expf(ebuf[7]);  // q_2047 = beta_2047 * exp(emit_2047)
    een = __expf(ebuf[6]);          // exp(emit_2046)

    // peel t = 2047..2041 to align groups of 8 (mask via per-step loads; off hot path)
#pragma unroll
    for (int pt = 0; pt < 7; ++pt) {
      const int t = 2047 - pt;
      float ee = een;                       // exp(emit_{t-1})
      een = __expf(ebuf[(t + 6) & 7]);      // emit_{t-2}
      float acc = rotdot48(q, Evp, a16, a32, a48, isr2, isr0);  // beta_{t-1}
      float mv  = mb[t];
      p = (mv != 0.0f) ? acc : p;
      ebuf[t & 7] = eb[(size_t)(t - 8) * NTAGS + jc];
      if (pt == 6) renorm(p, cl);
      q = p * ee;
    }
    for (int g = 0; g < 127; ++g) {
      const int t0 = 2040 - 8 * g;
      const uint32_t m8 = (uint32_t)__ballot(mnext != 0.0f) & 0xffu;  // bit u <-> t0-u
      mnext = mb[(size_t)(t0 - 8) - (lane & 7)];
      if (m8 == 0xffu) {
#pragma unroll
        for (int u = 0; u < 8; ++u) {
          const int t = t0 - u;               // down to 1025
          float ee = een;
          een = __expf(ebuf[(t + 6) & 7]);
          float acc = rotdot48(q, Evp, a16, a32, a48, isr2, isr0);
          p = acc;
          ebuf[t & 7] = eb[(size_t)(t - 8) * NTAGS + jc];
          if (u == 7) renorm(p, cl);
          q = p * ee;
        }
      } else {
#pragma unroll
        for (int u = 0; u < 8; ++u) {
          const int t = t0 - u;
          float ee = een;
          een = __expf(ebuf[(t + 6) & 7]);
          float acc = rotdot48(q, Evp, a16, a32, a48, isr2, isr0);
          p = ((m8 >> u) & 1u) ? acc : p;
          ebuf[t & 7] = eb[(size_t)(t - 8) * NTAGS + jc];
          if (u == 7) renorm(p, cl);
          q = p * ee;
        }
      }
    }
    if (lane < NTAGS) wb[b * NTAGS + lane] = __logf(p) + cl;
  }
}

// ---------- combine: one block, one thread per batch; no atomics ----------
// partition_b = lse(alpha_1024 + beta_1024); loss = mean(part - score).
// Old version did 512 device-scope atomicAdds to ONE address (cross-XCD
// cacheline ping-pong); now: per-thread value -> wave DPP reduce -> LDS ->
// single plain store. Deterministic.

extern "C" __global__ __launch_bounds__(512)
void crf_combine(const float* __restrict__ wa, const float* __restrict__ wb,
                 const float* __restrict__ wsc, const int* __restrict__ wcnt,
                 const int* __restrict__ tags, const float* __restrict__ endt,
                 float* __restrict__ out) {
  __shared__ float red[8];
  const int b = threadIdx.x;  // 512 threads = 512 batches
  float vv[NTAGS];
  float m = -1e30f;
#pragma unroll
  for (int j = 0; j < NTAGS; ++j) {
    vv[j] = wa[b * NTAGS + j] + wb[b * NTAGS + j];
    m = fmaxf(m, vv[j]);
  }
  float s = 0.0f;
#pragma unroll
  for (int j = 0; j < NTAGS; ++j) s += __expf(vv[j] - m);
  float part = m + __logf(s);
  const int   last  = wcnt[b] - 1;
  const float score = wsc[b] + endt[tags[(size_t)b * SLEN + last]];
  float val = (part - score) * (1.0f / (float)NB);
  float wsum = wred_sum(val);
  if ((b & 63) == 0) red[b >> 6] = wsum;
  __syncthreads();
  if (b == 0) {
    float t = 0.0f;
#pragma unroll
    for (int w = 0; w < 8; ++w) t += red[w];
    *out = t;
  }
}

// ---------- launch ----------

extern "C" void kernel_launch(void* const* d_in, const int* in_sizes, int n_in,
                              void* d_out, int out_size, void* d_ws, size_t ws_size,
                              hipStream_t stream) {
  const float* emis  = (const float*)d_in[0];
  const float* trans = (const float*)d_in[1];
  const float* stt   = (const float*)d_in[2];
  const float* ent   = (const float*)d_in[3];
  const int*   tags  = (const int*)d_in[4];
  const float* mask  = (const float*)d_in[5];

  float* wa   = (float*)d_ws;            // [NB][NTAGS]
  float* wb   = wa + NB * NTAGS;         // [NB][NTAGS]
  float* wsc  = wb + NB * NTAGS;         // [NB]
  int*   wcnt = (int*)(wsc + NB);        // [NB]

  crf_main<<<2 * NB + NB, 64, 0, stream>>>(emis, trans, stt, ent, tags, mask,
                                           wa, wb, wsc, wcnt);
  crf_combine<<<1, 512, 0, stream>>>(wa, wb, wsc, wcnt, tags, ent, (float*)d_out);
}